// Round 2
// baseline (10773.373 us; speedup 1.0000x reference)
//
#include <hip/hip_runtime.h>
#include <hip/hip_bf16.h>

#define DMODEL 256
#define S_TOT  70
#define BATCH  128
#define HEADS  8
#define DHEAD  32
#define PAST_N 50
#define FUT_N  20
#define LAYERS 3
#define FFD    1024

#define BM 32
#define BN 64
#define BK 16

// ---- decode weight-pack layout (dword offsets) ----
#define LSTRIDE  458752
#define OFF_QKV  0
#define OFF_WO   98304
#define OFF_CAQ  131072
#define OFF_CAO  163840
#define OFF_FF1  196608
#define OFF_FF2  327680
#define CKV_OFF  1376256
#define TOTAL_PK 1572864
#define NT 512

__device__ __forceinline__ float wave_sum64(float v) {
#pragma unroll
  for (int off = 32; off > 0; off >>= 1) v += __shfl_xor(v, off, 64);
  return v;
}
__device__ __forceinline__ float wave_max64(float v) {
#pragma unroll
  for (int off = 32; off > 0; off >>= 1) v = fmaxf(v, __shfl_xor(v, off, 64));
  return v;
}
__device__ __forceinline__ float gelu_f(float x) {
  return 0.5f * x * (1.0f + erff(x * 0.7071067811865476f));
}
__device__ __forceinline__ uint16_t f2bf(float v) {
  uint32_t b = __float_as_uint(v);
  return (uint16_t)((b + 0x7fffu + ((b >> 16) & 1u)) >> 16);
}
// block = 256 threads, one row of 256 elements
__device__ __forceinline__ float ln_norm_256(float x, float g, float b, float* sbuf, int tid) {
  float s = wave_sum64(x);
  if ((tid & 63) == 0) sbuf[tid >> 6] = s;
  __syncthreads();
  float mean = (sbuf[0] + sbuf[1] + sbuf[2] + sbuf[3]) * (1.0f / 256.0f);
  __syncthreads();
  float d = x - mean;
  float vs = wave_sum64(d * d);
  if ((tid & 63) == 0) sbuf[tid >> 6] = vs;
  __syncthreads();
  float var = (sbuf[0] + sbuf[1] + sbuf[2] + sbuf[3]) * (1.0f / 256.0f);
  return d * rsqrtf(var + 1e-5f) * g + b;
}

// ======================= prefill kernels (unchanged) =======================
__global__ __launch_bounds__(256) void k_gemm(
    const float* __restrict__ A, const float* __restrict__ W,
    const float* __restrict__ bias, const float* __restrict__ Rres,
    float* __restrict__ C, int M, int N, int K, int act, int outmode,
    float* __restrict__ qout, __hip_bfloat16* __restrict__ kc,
    __hip_bfloat16* __restrict__ vc, __hip_bfloat16* __restrict__ c6,
    int rows_per_b, int pos_base)
{
  __shared__ float As[BK][BM + 2];
  __shared__ float Ws[BK][BN + 4];
  const int tid = threadIdx.x;
  const int bm0 = blockIdx.y * BM;
  const int bn0 = blockIdx.x * BN;
  const int r = tid >> 4, c = tid & 15;
  const int am = tid >> 3, ak = (tid & 7) << 1;
  const int wn = tid >> 2, wk = (tid & 3) << 2;
  const float* Aptr = A + (size_t)(bm0 + am) * K + ak;
  const float* Wptr = W + (size_t)(bn0 + wn) * K + wk;
  float acc[2][4] = {{0.f, 0.f, 0.f, 0.f}, {0.f, 0.f, 0.f, 0.f}};
  for (int k0 = 0; k0 < K; k0 += BK) {
    float2 av = *(const float2*)(Aptr + k0);
    float4 wv = *(const float4*)(Wptr + k0);
    As[ak][am] = av.x;  As[ak + 1][am] = av.y;
    Ws[wk][wn] = wv.x;  Ws[wk + 1][wn] = wv.y;
    Ws[wk + 2][wn] = wv.z;  Ws[wk + 3][wn] = wv.w;
    __syncthreads();
#pragma unroll
    for (int kk = 0; kk < BK; kk++) {
      const float2 a = *(const float2*)&As[kk][r << 1];
      const float4 w = *(const float4*)&Ws[kk][c << 2];
      acc[0][0] += a.x * w.x; acc[0][1] += a.x * w.y;
      acc[0][2] += a.x * w.z; acc[0][3] += a.x * w.w;
      acc[1][0] += a.y * w.x; acc[1][1] += a.y * w.y;
      acc[1][2] += a.y * w.z; acc[1][3] += a.y * w.w;
    }
    __syncthreads();
  }
#pragma unroll
  for (int i = 0; i < 2; i++) {
    const int row = bm0 + (r << 1) + i;
    const int b = row / rows_per_b;
    const int t = pos_base + row % rows_per_b;
#pragma unroll
    for (int j = 0; j < 4; j++) {
      const int n = bn0 + (c << 2) + j;
      float v = acc[i][j] + bias[n];
      if (Rres) v += Rres[(size_t)row * N + n];
      if (act) v = gelu_f(v);
      if (outmode == 0) {
        C[(size_t)row * N + n] = v;
      } else if (outmode == 1) {
        if (n < 256) qout[(size_t)row * DMODEL + n] = v;
        else if (n < 512) kc[((size_t)b * S_TOT + t) * DMODEL + (n - 256)] = __float2bfloat16(v);
        else vc[((size_t)b * S_TOT + t) * DMODEL + (n - 512)] = __float2bfloat16(v);
      } else {
        const int j6 = n >> 8;
        c6[(size_t)j6 * ((size_t)BATCH * S_TOT * DMODEL) +
           ((size_t)b * S_TOT + t) * DMODEL + (n & 255)] = __float2bfloat16(v);
      }
    }
  }
}

__global__ __launch_bounds__(64) void k_attn(
    const float* __restrict__ qbuf, const __hip_bfloat16* __restrict__ kc,
    const __hip_bfloat16* __restrict__ vc, float* __restrict__ outb,
    int rows_per_b, int pos_base)
{
  __shared__ float qs[DHEAD];
  __shared__ float ss[S_TOT];
  const int bid = blockIdx.x;
  const int h = bid & (HEADS - 1);
  const int row = bid >> 3;
  const int b = row / rows_per_b;
  const int t = pos_base + row % rows_per_b;
  const int nk = t + 1;
  const int lane = threadIdx.x;
  if (lane < DHEAD) qs[lane] = qbuf[(size_t)row * DMODEL + h * DHEAD + lane];
  __syncthreads();
  float mx = -1e30f;
  for (int k0 = lane; k0 < nk; k0 += 64) {
    const __hip_bfloat16* kp = kc + ((size_t)b * S_TOT + k0) * DMODEL + h * DHEAD;
    float s = 0.f;
#pragma unroll
    for (int i = 0; i < DHEAD; i++) s += qs[i] * __bfloat162float(kp[i]);
    s *= 0.17677669529663687f;
    ss[k0] = s;
    mx = fmaxf(mx, s);
  }
  mx = wave_max64(mx);
  float sum = 0.f;
  for (int k0 = lane; k0 < nk; k0 += 64) {
    float e = expf(ss[k0] - mx);
    ss[k0] = e;
    sum += e;
  }
  sum = wave_sum64(sum);
  __syncthreads();
  const float inv = 1.0f / sum;
  if (lane < DHEAD) {
    float o = 0.f;
    for (int k0 = 0; k0 < nk; k0++)
      o += ss[k0] * __bfloat162float(vc[((size_t)b * S_TOT + k0) * DMODEL + h * DHEAD + lane]);
    outb[(size_t)row * DMODEL + h * DHEAD + lane] = o * inv;
  }
}

__global__ __launch_bounds__(256) void k_ln(
    const float* __restrict__ Z, const float* __restrict__ g,
    const float* __restrict__ b, float* __restrict__ out)
{
  __shared__ float sbuf[4];
  const int row = blockIdx.x, tid = threadIdx.x;
  float x = Z[(size_t)row * DMODEL + tid];
  out[(size_t)row * DMODEL + tid] = ln_norm_256(x, g[tid], b[tid], sbuf, tid);
}

__global__ __launch_bounds__(256) void k_embed(
    const float* __restrict__ past, const float* __restrict__ in_W,
    const float* __restrict__ in_b, const float* __restrict__ pos_emb,
    const float* __restrict__ ln_w, const float* __restrict__ ln_b,
    float* __restrict__ Aout)
{
  __shared__ float sbuf[4];
  const int rowid = blockIdx.x;
  const int b = rowid / PAST_N, t = rowid % PAST_N;
  const int tid = threadIdx.x;
  float dx = 0.f, dy = 0.f;
  if (t > 0) {
    dx = past[((size_t)b * PAST_N + t) * 2 + 0] - past[((size_t)b * PAST_N + t - 1) * 2 + 0];
    dy = past[((size_t)b * PAST_N + t) * 2 + 1] - past[((size_t)b * PAST_N + t - 1) * 2 + 1];
  }
  float v = in_W[tid * 2 + 0] * dx + in_W[tid * 2 + 1] * dy + in_b[tid] +
            pos_emb[(size_t)t * DMODEL + tid];
  Aout[(size_t)rowid * DMODEL + tid] = ln_norm_256(v, ln_w[tid], ln_b[tid], sbuf, tid);
}

__global__ __launch_bounds__(256) void k_prepack(
    const float* __restrict__ caW, const float* __restrict__ cab,
    float* __restrict__ Wckv, float* __restrict__ bckv)
{
  const int n = blockIdx.x, tid = threadIdx.x;
  const int j = n >> 8, dcol = n & 255;
  const int l = j >> 1, kv = j & 1;
  const int srow = l * 768 + 256 + kv * 256 + dcol;
  Wckv[(size_t)n * 256 + tid] = caW[(size_t)srow * 256 + tid];
  if (tid == 0) bckv[n] = cab[l * 768 + 256 + kv * 256 + dcol];
}

__global__ __launch_bounds__(64) void k_readout(
    const float* __restrict__ X, const float* __restrict__ out_W,
    const float* __restrict__ out_b, const float* __restrict__ past,
    float* __restrict__ cur, float* __restrict__ ndb, float* __restrict__ out,
    int rows_per_b, int s, int init)
{
  const int b = blockIdx.x, lane = threadIdx.x;
  const int row = b * rows_per_b + rows_per_b - 1;
  float p0 = 0.f, p1 = 0.f;
  for (int d = lane; d < DMODEL; d += 64) {
    const float xv = X[(size_t)row * DMODEL + d];
    p0 += xv * out_W[d];
    p1 += xv * out_W[DMODEL + d];
  }
  p0 = wave_sum64(p0);
  p1 = wave_sum64(p1);
  if (lane == 0) {
    const float nd0 = p0 + out_b[0];
    const float nd1 = p1 + out_b[1];
    float c0, c1;
    if (init) {
      c0 = past[((size_t)b * PAST_N + PAST_N - 1) * 2 + 0];
      c1 = past[((size_t)b * PAST_N + PAST_N - 1) * 2 + 1];
    } else {
      c0 = cur[b * 2 + 0];
      c1 = cur[b * 2 + 1];
    }
    c0 += nd0; c1 += nd1;
    cur[b * 2 + 0] = c0; cur[b * 2 + 1] = c1;
    ndb[b * 2 + 0] = nd0; ndb[b * 2 + 1] = nd1;
    out[((size_t)b * FUT_N + s) * 2 + 0] = c0;
    out[((size_t)b * FUT_N + s) * 2 + 1] = c1;
  }
}

// ======================= decode weight pre-pack =======================
// Wpk: transposed bf16-pair layout [K/2][N], dword = (bf16(W[n][2k2+1])<<16)|bf16(W[n][2k2])
__global__ __launch_bounds__(256) void k_pack_decode(
    const float* __restrict__ sa_Wqkv, const float* __restrict__ sa_Wo,
    const float* __restrict__ ca_Wqkv, const float* __restrict__ ca_Wo,
    const float* __restrict__ ff1_W, const float* __restrict__ ff2_W,
    uint32_t* __restrict__ Wpk)
{
  const int g = blockIdx.x * 256 + threadIdx.x;
  if (g >= TOTAL_PK) return;
  const float* src;
  int k2;
  if (g < CKV_OFF) {
    const int l = g / LSTRIDE, r = g % LSTRIDE;
    if (r < OFF_WO)       { int rr = r;            k2 = rr / 768;  int n = rr % 768;  src = sa_Wqkv + (size_t)l * 196608 + (size_t)n * 256; }
    else if (r < OFF_CAQ) { int rr = r - OFF_WO;   k2 = rr / 256;  int n = rr % 256;  src = sa_Wo   + (size_t)l * 65536  + (size_t)n * 256; }
    else if (r < OFF_CAO) { int rr = r - OFF_CAQ;  k2 = rr / 256;  int n = rr % 256;  src = ca_Wqkv + (size_t)l * 196608 + (size_t)n * 256; }
    else if (r < OFF_FF1) { int rr = r - OFF_CAO;  k2 = rr / 256;  int n = rr % 256;  src = ca_Wo   + (size_t)l * 65536  + (size_t)n * 256; }
    else if (r < OFF_FF2) { int rr = r - OFF_FF1;  k2 = rr / 1024; int n = rr % 1024; src = ff1_W   + (size_t)l * 262144 + (size_t)n * 256; }
    else                  { int rr = r - OFF_FF2;  k2 = rr / 256;  int n = rr % 256;  src = ff2_W   + (size_t)l * 262144 + (size_t)n * 1024; }
  } else {
    const int r = g - CKV_OFF;
    k2 = r / 1536;
    const int n = r % 1536;
    const int j = n >> 8, dcol = n & 255, l = j >> 1, kv = j & 1;
    src = ca_Wqkv + (size_t)l * 196608 + (size_t)(256 + kv * 256 + dcol) * 256;
  }
  const uint32_t u = ((uint32_t)f2bf(src[2 * k2 + 1]) << 16) | (uint32_t)f2bf(src[2 * k2]);
  Wpk[g] = u;
}

// ======================= fused 19-step decode =======================
// one workgroup (512 thr = 8 waves) per batch element; runs steps 1..19 internally
__global__ __launch_bounds__(NT) void k_decode(
    const uint32_t* __restrict__ Wpk, const float* __restrict__ bckv,
    const float* __restrict__ in_W, const float* __restrict__ in_b,
    const float* __restrict__ pos_emb,
    const float* __restrict__ ln0_w, const float* __restrict__ ln0_b,
    const float* __restrict__ sa_bqkv, const float* __restrict__ sa_bo,
    const float* __restrict__ ca_bqkv, const float* __restrict__ ca_bo,
    const float* __restrict__ ff1_b, const float* __restrict__ ff2_b,
    const float* __restrict__ ln1_w, const float* __restrict__ ln1_b,
    const float* __restrict__ ln2_w, const float* __restrict__ ln2_b,
    const float* __restrict__ ln3_w, const float* __restrict__ ln3_b,
    const float* __restrict__ out_W, const float* __restrict__ out_b,
    __hip_bfloat16* __restrict__ Ksa, __hip_bfloat16* __restrict__ Vsa,
    __hip_bfloat16* __restrict__ C6,
    const float* __restrict__ ndb, const float* __restrict__ cur,
    float* __restrict__ out)
{
  const int b = blockIdx.x;
  const int tid = threadIdx.x;
  const size_t slab = (size_t)BATCH * S_TOT * DMODEL;

  __shared__ __align__(16) float x[256];
  __shared__ __align__(16) float xt[256];
  __shared__ __align__(16) float q[256];
  __shared__ __align__(16) float att[256];
  __shared__ __align__(16) float hbuf[1024];
  __shared__ float pred[NT];
  __shared__ float kn[256], vn[256];
  __shared__ __align__(16) float ckvn[1536];
  __shared__ float ss[8][72];
  __shared__ float sb[8], sb2[8];
  __shared__ float ndc[4];

  if (tid == 0) {
    ndc[0] = ndb[2 * b];     ndc[1] = ndb[2 * b + 1];
    ndc[2] = cur[2 * b];     ndc[3] = cur[2 * b + 1];
  }
  __syncthreads();

  // single-pass LN over a 256-row in LDS (all 512 threads must call)
  auto ln_row = [&](float* row, const float* g, const float* bb) {
    float v = (tid < 256) ? row[tid] : 0.f;
    float s  = wave_sum64(v);
    float s2 = wave_sum64(v * v);
    if ((tid & 63) == 0) { sb[tid >> 6] = s; sb2[tid >> 6] = s2; }
    __syncthreads();
    float mean = (sb[0] + sb[1] + sb[2] + sb[3]) * (1.0f / 256.0f);
    float ex2  = (sb2[0] + sb2[1] + sb2[2] + sb2[3]) * (1.0f / 256.0f);
    float var = ex2 - mean * mean;
    if (tid < 256) row[tid] = (v - mean) * rsqrtf(var + 1e-5f) * g[tid] + bb[tid];
    __syncthreads();
  };

  // GEMV, K=256, N in {768,1024,1536}: n-strided across 512 threads
  auto gemvN = [&](const uint32_t* Wp, int N, const float* xin, auto&& emit) {
    const float2* x2 = (const float2*)xin;
    for (int n = tid; n < N; n += NT) {
      float acc = 0.f;
      const uint32_t* col = Wp + n;
#pragma unroll 4
      for (int k2 = 0; k2 < 128; k2++) {
        uint32_t w = col[(size_t)k2 * N];
        float2 xv = x2[k2];
        acc += __uint_as_float(w << 16) * xv.x;
        acc += __uint_as_float(w & 0xffff0000u) * xv.y;
      }
      emit(n, acc);
    }
  };

  // GEMV, N=256, split-K across the two 256-thread halves -> pred[]
  auto gemv256 = [&](const uint32_t* Wp, int K2total, const float* xin) {
    const float2* x2 = (const float2*)xin;
    const int n = tid & 255, half = tid >> 8;
    const int k2b = half * (K2total >> 1), k2e = k2b + (K2total >> 1);
    float acc = 0.f;
    const uint32_t* col = Wp + n;
    for (int k2 = k2b; k2 < k2e; k2++) {
      uint32_t w = col[(size_t)k2 * 256];
      float2 xv = x2[k2];
      acc += __uint_as_float(w << 16) * xv.x;
      acc += __uint_as_float(w & 0xffff0000u) * xv.y;
    }
    pred[tid] = acc;
  };

  // attention: 1 wave = 1 head; keys 0..pos-1 from bf16 cache, key pos from LDS
  auto attn8 = [&](const __hip_bfloat16* Kc, const __hip_bfloat16* Vc,
                   const float* knw, const float* vnw, int pos) {
    const int h = tid >> 6, lane = tid & 63;
    const float* qh = q + h * 32;
    float mx = -1e30f;
    for (int k0 = lane; k0 <= pos; k0 += 64) {
      float s = 0.f;
      if (k0 == pos) {
        const float* kp = knw + h * 32;
#pragma unroll
        for (int i = 0; i < 32; i++) s += qh[i] * kp[i];
      } else {
        const uint32_t* kp = (const uint32_t*)(Kc + ((size_t)b * S_TOT + k0) * DMODEL + h * 32);
#pragma unroll
        for (int i = 0; i < 16; i++) {
          uint32_t w = kp[i];
          s += __uint_as_float(w << 16) * qh[2 * i];
          s += __uint_as_float(w & 0xffff0000u) * qh[2 * i + 1];
        }
      }
      s *= 0.17677669529663687f;
      ss[h][k0] = s;
      mx = fmaxf(mx, s);
    }
    mx = wave_max64(mx);
    float sum = 0.f;
    for (int k0 = lane; k0 <= pos; k0 += 64) {
      float e = __expf(ss[h][k0] - mx);
      ss[h][k0] = e;
      sum += e;
    }
    sum = wave_sum64(sum);
    const float inv = 1.0f / sum;
    if (lane < 32) {
      float o = 0.f;
      for (int k0 = 0; k0 < pos; k0++)
        o += ss[h][k0] * __bfloat162float(Vc[((size_t)b * S_TOT + k0) * DMODEL + h * 32 + lane]);
      o += ss[h][pos] * vnw[h * 32 + lane];
      att[h * 32 + lane] = o * inv;
    }
  };

  for (int s = 1; s < FUT_N; s++) {
    const int pos = PAST_N - 1 + s;
    // 1. token embed + LN0 -> xt (mem row); copy to x
    if (tid < 256) {
      xt[tid] = in_W[tid * 2] * ndc[0] + in_W[tid * 2 + 1] * ndc[1] + in_b[tid] +
                pos_emb[(size_t)pos * DMODEL + tid];
    }
    __syncthreads();
    ln_row(xt, ln0_w, ln0_b);
    if (tid < 256) x[tid] = xt[tid];
    __syncthreads();
    // 2. CA K/V for this token: append to C6 + keep in LDS
    gemvN(Wpk + CKV_OFF, 1536, xt, [&](int n, float acc) {
      float v = acc + bckv[n];
      ckvn[n] = v;
      const int j = n >> 8;
      C6[(size_t)j * slab + ((size_t)b * S_TOT + pos) * DMODEL + (n & 255)] = __float2bfloat16(v);
    });
    __syncthreads();

    for (int l = 0; l < LAYERS; l++) {
      const uint32_t* Wl = Wpk + (size_t)l * LSTRIDE;
      // a. SA qkv
      gemvN(Wl + OFF_QKV, 768, x, [&](int n, float acc) {
        float v = acc + sa_bqkv[l * 768 + n];
        if (n < 256) q[n] = v;
        else if (n < 512) {
          kn[n - 256] = v;
          Ksa[(size_t)l * slab + ((size_t)b * S_TOT + pos) * DMODEL + (n - 256)] = __float2bfloat16(v);
        } else {
          vn[n - 512] = v;
          Vsa[(size_t)l * slab + ((size_t)b * S_TOT + pos) * DMODEL + (n - 512)] = __float2bfloat16(v);
        }
      });
      __syncthreads();
      // b. SA attention
      attn8(Ksa + (size_t)l * slab, Vsa + (size_t)l * slab, kn, vn, pos);
      __syncthreads();
      // c. Wo + residual + LN1
      gemv256(Wl + OFF_WO, 128, att);
      __syncthreads();
      if (tid < 256) x[tid] = x[tid] + pred[tid] + pred[tid + 256] + sa_bo[l * 256 + tid];
      __syncthreads();
      ln_row(x, ln1_w + l * 256, ln1_b + l * 256);
      // d. CA q
      gemv256(Wl + OFF_CAQ, 128, x);
      __syncthreads();
      if (tid < 256) q[tid] = pred[tid] + pred[tid + 256] + ca_bqkv[l * 768 + tid];
      __syncthreads();
      // e. CA attention over C6 caches
      attn8(C6 + (size_t)(2 * l) * slab, C6 + (size_t)(2 * l + 1) * slab,
            ckvn + l * 512, ckvn + l * 512 + 256, pos);
      __syncthreads();
      // f. CA Wo + residual + LN2
      gemv256(Wl + OFF_CAO, 128, att);
      __syncthreads();
      if (tid < 256) x[tid] = x[tid] + pred[tid] + pred[tid + 256] + ca_bo[l * 256 + tid];
      __syncthreads();
      ln_row(x, ln2_w + l * 256, ln2_b + l * 256);
      // g. FF1 + gelu
      gemvN(Wl + OFF_FF1, 1024, x, [&](int n, float acc) {
        hbuf[n] = gelu_f(acc + ff1_b[l * 1024 + n]);
      });
      __syncthreads();
      // h. FF2 (K=1024) + residual + LN3
      gemv256(Wl + OFF_FF2, 512, hbuf);
      __syncthreads();
      if (tid < 256) x[tid] = x[tid] + pred[tid] + pred[tid + 256] + ff2_b[l * 256 + tid];
      __syncthreads();
      ln_row(x, ln3_w + l * 256, ln3_b + l * 256);
    }

    // readout: nd = x @ out_W^T + out_b ; cur += nd ; emit
    {
      const int lane = tid & 63;
      if (tid < 128) {
        const int d0 = tid >> 6;
        float p = 0.f;
        for (int d = lane; d < DMODEL; d += 64) p += x[d] * out_W[d0 * DMODEL + d];
        p = wave_sum64(p);
        if (lane == 0) {
          const float nd = p + out_b[d0];
          ndc[d0] = nd;
          const float c = ndc[2 + d0] + nd;
          ndc[2 + d0] = c;
          out[((size_t)b * FUT_N + s) * 2 + d0] = c;
        }
      }
      __syncthreads();
    }
  }
}

// ======================= host launch =======================
extern "C" void kernel_launch(void* const* d_in, const int* in_sizes, int n_in,
                              void* d_out, int out_size, void* d_ws, size_t ws_size,
                              hipStream_t stream)
{
  const float* past    = (const float*)d_in[0];
  const float* in_W    = (const float*)d_in[1];
  const float* in_b    = (const float*)d_in[2];
  const float* pos_emb = (const float*)d_in[3];
  const float* ln0_w   = (const float*)d_in[4];
  const float* ln0_b   = (const float*)d_in[5];
  const float* sa_Wqkv = (const float*)d_in[6];
  const float* sa_bqkv = (const float*)d_in[7];
  const float* sa_Wo   = (const float*)d_in[8];
  const float* sa_bo   = (const float*)d_in[9];
  const float* ca_Wqkv = (const float*)d_in[10];
  const float* ca_bqkv = (const float*)d_in[11];
  const float* ca_Wo   = (const float*)d_in[12];
  const float* ca_bo   = (const float*)d_in[13];
  const float* ff1_W   = (const float*)d_in[14];
  const float* ff1_b   = (const float*)d_in[15];
  const float* ff2_W   = (const float*)d_in[16];
  const float* ff2_b   = (const float*)d_in[17];
  const float* ln1_w   = (const float*)d_in[18];
  const float* ln1_b   = (const float*)d_in[19];
  const float* ln2_w   = (const float*)d_in[20];
  const float* ln2_b   = (const float*)d_in[21];
  const float* ln3_w   = (const float*)d_in[22];
  const float* ln3_b   = (const float*)d_in[23];
  const float* out_W   = (const float*)d_in[24];
  const float* out_b   = (const float*)d_in[25];
  float* out = (float*)d_out;

  const size_t Mpre = (size_t)BATCH * PAST_N;              // 6400
  const size_t slab = (size_t)BATCH * S_TOT * DMODEL;      // 2,293,760

  float* ws_f = (float*)d_ws;
  float* A    = ws_f;
  float* Bb   = A + Mpre * DMODEL;
  float* qb   = Bb + Mpre * DMODEL;
  float* at   = qb + Mpre * DMODEL;
  float* hb   = at + Mpre * DMODEL;
  float* Wckv = hb + Mpre * FFD;
  float* bckv = Wckv + (size_t)1536 * 256;
  float* ndb  = bckv + 1536;
  float* cur  = ndb + 256;
  __hip_bfloat16* Ksa = (__hip_bfloat16*)(cur + 256);
  __hip_bfloat16* Vsa = Ksa + 3 * slab;
  __hip_bfloat16* C6  = Vsa + 3 * slab;
  uint32_t* Wpk = (uint32_t*)hb;  // aliases hb: free after prefill, used only by decode

  const size_t need = ((size_t)(C6 + 6 * slab) - (size_t)d_ws);
  if (ws_size < need) return;

  auto layer = [&](int l, int M, int rpb, int pbase) {
    const float* Wqkv = sa_Wqkv + (size_t)l * 768 * 256;
    __hip_bfloat16* kcl = Ksa + (size_t)l * slab;
    __hip_bfloat16* vcl = Vsa + (size_t)l * slab;
    k_gemm<<<dim3(768 / BN, M / BM), 256, 0, stream>>>(
        A, Wqkv, sa_bqkv + l * 768, nullptr, nullptr, M, 768, 256, 0, 1,
        qb, kcl, vcl, nullptr, rpb, pbase);
    k_attn<<<M * HEADS, 64, 0, stream>>>(qb, kcl, vcl, at, rpb, pbase);
    k_gemm<<<dim3(256 / BN, M / BM), 256, 0, stream>>>(
        at, sa_Wo + (size_t)l * 65536, sa_bo + l * 256, A, Bb, M, 256, 256, 0, 0,
        nullptr, nullptr, nullptr, nullptr, 1, 0);
    k_ln<<<M, 256, 0, stream>>>(Bb, ln1_w + l * 256, ln1_b + l * 256, A);
    k_gemm<<<dim3(256 / BN, M / BM), 256, 0, stream>>>(
        A, ca_Wqkv + (size_t)l * 768 * 256, ca_bqkv + l * 768, nullptr, qb,
        M, 256, 256, 0, 0, nullptr, nullptr, nullptr, nullptr, 1, 0);
    k_attn<<<M * HEADS, 64, 0, stream>>>(
        qb, C6 + (size_t)(2 * l) * slab, C6 + (size_t)(2 * l + 1) * slab, at, rpb, pbase);
    k_gemm<<<dim3(256 / BN, M / BM), 256, 0, stream>>>(
        at, ca_Wo + (size_t)l * 65536, ca_bo + l * 256, A, Bb, M, 256, 256, 0, 0,
        nullptr, nullptr, nullptr, nullptr, 1, 0);
    k_ln<<<M, 256, 0, stream>>>(Bb, ln2_w + l * 256, ln2_b + l * 256, A);
    k_gemm<<<dim3(FFD / BN, M / BM), 256, 0, stream>>>(
        A, ff1_W + (size_t)l * FFD * 256, ff1_b + l * FFD, nullptr, hb,
        M, FFD, 256, 1, 0, nullptr, nullptr, nullptr, nullptr, 1, 0);
    k_gemm<<<dim3(256 / BN, M / BM), 256, 0, stream>>>(
        hb, ff2_W + (size_t)l * 256 * FFD, ff2_b + l * 256, A, Bb, M, 256, FFD, 0, 0,
        nullptr, nullptr, nullptr, nullptr, 1, 0);
    k_ln<<<M, 256, 0, stream>>>(Bb, ln3_w + l * 256, ln3_b + l * 256, A);
  };

  // ---- prefill over past 50 positions ----
  k_prepack<<<1536, 256, 0, stream>>>(ca_Wqkv, ca_bqkv, Wckv, bckv);
  k_embed<<<(int)Mpre, 256, 0, stream>>>(past, in_W, in_b, pos_emb, ln0_w, ln0_b, A);
  k_gemm<<<dim3(1536 / BN, (int)Mpre / BM), 256, 0, stream>>>(
      A, Wckv, bckv, nullptr, nullptr, (int)Mpre, 1536, 256, 0, 2,
      nullptr, nullptr, nullptr, C6, PAST_N, 0);
  for (int l = 0; l < LAYERS; l++) layer(l, (int)Mpre, PAST_N, 0);
  k_readout<<<BATCH, 64, 0, stream>>>(A, out_W, out_b, past, cur, ndb, out, PAST_N, 0, 1);

  // ---- pack decode weights (into hb scratch, free after prefill) ----
  k_pack_decode<<<(TOTAL_PK + 255) / 256, 256, 0, stream>>>(
      sa_Wqkv, sa_Wo, ca_Wqkv, ca_Wo, ff1_W, ff2_W, Wpk);

  // ---- fused 19-step decode: one WG per batch element ----
  k_decode<<<BATCH, NT, 0, stream>>>(
      Wpk, bckv, in_W, in_b, pos_emb, ln0_w, ln0_b,
      sa_bqkv, sa_bo, ca_bqkv, ca_bo, ff1_b, ff2_b,
      ln1_w, ln1_b, ln2_w, ln2_b, ln3_w, ln3_b,
      out_W, out_b, Ksa, Vsa, C6, ndb, cur, out);
}

// Round 3
// 7630.678 us; speedup vs baseline: 1.4119x; 1.4119x over previous
//
#include <hip/hip_runtime.h>
#include <hip/hip_bf16.h>

#define DMODEL 256
#define S_TOT  70
#define BATCH  128
#define HEADS  8
#define DHEAD  32
#define PAST_N 50
#define FUT_N  20
#define LAYERS 3
#define FFD    1024

#define BM 32
#define BN 64
#define BK 16

// ---- decode weight-pack layout (uint4 offsets). uint4 = 8 bf16 (k-major) ----
#define LSTRIDE4  114688
#define OFF4_QKV  0
#define OFF4_WO   24576
#define OFF4_CAQ  32768
#define OFF4_CAO  40960
#define OFF4_FF1  49152
#define OFF4_FF2  81920
#define CKV4_OFF  344064
#define TOTAL4    393216
#define NT 512

__device__ __forceinline__ float wave_sum64(float v) {
#pragma unroll
  for (int off = 32; off > 0; off >>= 1) v += __shfl_xor(v, off, 64);
  return v;
}
__device__ __forceinline__ float wave_max64(float v) {
#pragma unroll
  for (int off = 32; off > 0; off >>= 1) v = fmaxf(v, __shfl_xor(v, off, 64));
  return v;
}
__device__ __forceinline__ float gelu_f(float x) {
  return 0.5f * x * (1.0f + erff(x * 0.7071067811865476f));
}
__device__ __forceinline__ uint16_t f2bf(float v) {
  uint32_t b = __float_as_uint(v);
  return (uint16_t)((b + 0x7fffu + ((b >> 16) & 1u)) >> 16);
}
__device__ __forceinline__ float bl16(uint32_t w) { return __uint_as_float(w << 16); }
__device__ __forceinline__ float bh16(uint32_t w) { return __uint_as_float(w & 0xffff0000u); }

// block = 256 threads, one row of 256 elements
__device__ __forceinline__ float ln_norm_256(float x, float g, float b, float* sbuf, int tid) {
  float s = wave_sum64(x);
  if ((tid & 63) == 0) sbuf[tid >> 6] = s;
  __syncthreads();
  float mean = (sbuf[0] + sbuf[1] + sbuf[2] + sbuf[3]) * (1.0f / 256.0f);
  __syncthreads();
  float d = x - mean;
  float vs = wave_sum64(d * d);
  if ((tid & 63) == 0) sbuf[tid >> 6] = vs;
  __syncthreads();
  float var = (sbuf[0] + sbuf[1] + sbuf[2] + sbuf[3]) * (1.0f / 256.0f);
  return d * rsqrtf(var + 1e-5f) * g + b;
}

// ======================= prefill kernels (unchanged) =======================
__global__ __launch_bounds__(256) void k_gemm(
    const float* __restrict__ A, const float* __restrict__ W,
    const float* __restrict__ bias, const float* __restrict__ Rres,
    float* __restrict__ C, int M, int N, int K, int act, int outmode,
    float* __restrict__ qout, __hip_bfloat16* __restrict__ kc,
    __hip_bfloat16* __restrict__ vc, __hip_bfloat16* __restrict__ c6,
    int rows_per_b, int pos_base)
{
  __shared__ float As[BK][BM + 2];
  __shared__ float Ws[BK][BN + 4];
  const int tid = threadIdx.x;
  const int bm0 = blockIdx.y * BM;
  const int bn0 = blockIdx.x * BN;
  const int r = tid >> 4, c = tid & 15;
  const int am = tid >> 3, ak = (tid & 7) << 1;
  const int wn = tid >> 2, wk = (tid & 3) << 2;
  const float* Aptr = A + (size_t)(bm0 + am) * K + ak;
  const float* Wptr = W + (size_t)(bn0 + wn) * K + wk;
  float acc[2][4] = {{0.f, 0.f, 0.f, 0.f}, {0.f, 0.f, 0.f, 0.f}};
  for (int k0 = 0; k0 < K; k0 += BK) {
    float2 av = *(const float2*)(Aptr + k0);
    float4 wv = *(const float4*)(Wptr + k0);
    As[ak][am] = av.x;  As[ak + 1][am] = av.y;
    Ws[wk][wn] = wv.x;  Ws[wk + 1][wn] = wv.y;
    Ws[wk + 2][wn] = wv.z;  Ws[wk + 3][wn] = wv.w;
    __syncthreads();
#pragma unroll
    for (int kk = 0; kk < BK; kk++) {
      const float2 a = *(const float2*)&As[kk][r << 1];
      const float4 w = *(const float4*)&Ws[kk][c << 2];
      acc[0][0] += a.x * w.x; acc[0][1] += a.x * w.y;
      acc[0][2] += a.x * w.z; acc[0][3] += a.x * w.w;
      acc[1][0] += a.y * w.x; acc[1][1] += a.y * w.y;
      acc[1][2] += a.y * w.z; acc[1][3] += a.y * w.w;
    }
    __syncthreads();
  }
#pragma unroll
  for (int i = 0; i < 2; i++) {
    const int row = bm0 + (r << 1) + i;
    const int b = row / rows_per_b;
    const int t = pos_base + row % rows_per_b;
#pragma unroll
    for (int j = 0; j < 4; j++) {
      const int n = bn0 + (c << 2) + j;
      float v = acc[i][j] + bias[n];
      if (Rres) v += Rres[(size_t)row * N + n];
      if (act) v = gelu_f(v);
      if (outmode == 0) {
        C[(size_t)row * N + n] = v;
      } else if (outmode == 1) {
        if (n < 256) qout[(size_t)row * DMODEL + n] = v;
        else if (n < 512) kc[((size_t)b * S_TOT + t) * DMODEL + (n - 256)] = __float2bfloat16(v);
        else vc[((size_t)b * S_TOT + t) * DMODEL + (n - 512)] = __float2bfloat16(v);
      } else {
        const int j6 = n >> 8;
        c6[(size_t)j6 * ((size_t)BATCH * S_TOT * DMODEL) +
           ((size_t)b * S_TOT + t) * DMODEL + (n & 255)] = __float2bfloat16(v);
      }
    }
  }
}

__global__ __launch_bounds__(64) void k_attn(
    const float* __restrict__ qbuf, const __hip_bfloat16* __restrict__ kc,
    const __hip_bfloat16* __restrict__ vc, float* __restrict__ outb,
    int rows_per_b, int pos_base)
{
  __shared__ float qs[DHEAD];
  __shared__ float ss[S_TOT];
  const int bid = blockIdx.x;
  const int h = bid & (HEADS - 1);
  const int row = bid >> 3;
  const int b = row / rows_per_b;
  const int t = pos_base + row % rows_per_b;
  const int nk = t + 1;
  const int lane = threadIdx.x;
  if (lane < DHEAD) qs[lane] = qbuf[(size_t)row * DMODEL + h * DHEAD + lane];
  __syncthreads();
  float mx = -1e30f;
  for (int k0 = lane; k0 < nk; k0 += 64) {
    const __hip_bfloat16* kp = kc + ((size_t)b * S_TOT + k0) * DMODEL + h * DHEAD;
    float s = 0.f;
#pragma unroll
    for (int i = 0; i < DHEAD; i++) s += qs[i] * __bfloat162float(kp[i]);
    s *= 0.17677669529663687f;
    ss[k0] = s;
    mx = fmaxf(mx, s);
  }
  mx = wave_max64(mx);
  float sum = 0.f;
  for (int k0 = lane; k0 < nk; k0 += 64) {
    float e = expf(ss[k0] - mx);
    ss[k0] = e;
    sum += e;
  }
  sum = wave_sum64(sum);
  __syncthreads();
  const float inv = 1.0f / sum;
  if (lane < DHEAD) {
    float o = 0.f;
    for (int k0 = 0; k0 < nk; k0++)
      o += ss[k0] * __bfloat162float(vc[((size_t)b * S_TOT + k0) * DMODEL + h * DHEAD + lane]);
    outb[(size_t)row * DMODEL + h * DHEAD + lane] = o * inv;
  }
}

__global__ __launch_bounds__(256) void k_ln(
    const float* __restrict__ Z, const float* __restrict__ g,
    const float* __restrict__ b, float* __restrict__ out)
{
  __shared__ float sbuf[4];
  const int row = blockIdx.x, tid = threadIdx.x;
  float x = Z[(size_t)row * DMODEL + tid];
  out[(size_t)row * DMODEL + tid] = ln_norm_256(x, g[tid], b[tid], sbuf, tid);
}

__global__ __launch_bounds__(256) void k_embed(
    const float* __restrict__ past, const float* __restrict__ in_W,
    const float* __restrict__ in_b, const float* __restrict__ pos_emb,
    const float* __restrict__ ln_w, const float* __restrict__ ln_b,
    float* __restrict__ Aout)
{
  __shared__ float sbuf[4];
  const int rowid = blockIdx.x;
  const int b = rowid / PAST_N, t = rowid % PAST_N;
  const int tid = threadIdx.x;
  float dx = 0.f, dy = 0.f;
  if (t > 0) {
    dx = past[((size_t)b * PAST_N + t) * 2 + 0] - past[((size_t)b * PAST_N + t - 1) * 2 + 0];
    dy = past[((size_t)b * PAST_N + t) * 2 + 1] - past[((size_t)b * PAST_N + t - 1) * 2 + 1];
  }
  float v = in_W[tid * 2 + 0] * dx + in_W[tid * 2 + 1] * dy + in_b[tid] +
            pos_emb[(size_t)t * DMODEL + tid];
  Aout[(size_t)rowid * DMODEL + tid] = ln_norm_256(v, ln_w[tid], ln_b[tid], sbuf, tid);
}

__global__ __launch_bounds__(256) void k_prepack(
    const float* __restrict__ caW, const float* __restrict__ cab,
    float* __restrict__ Wckv, float* __restrict__ bckv)
{
  const int n = blockIdx.x, tid = threadIdx.x;
  const int j = n >> 8, dcol = n & 255;
  const int l = j >> 1, kv = j & 1;
  const int srow = l * 768 + 256 + kv * 256 + dcol;
  Wckv[(size_t)n * 256 + tid] = caW[(size_t)srow * 256 + tid];
  if (tid == 0) bckv[n] = cab[l * 768 + 256 + kv * 256 + dcol];
}

__global__ __launch_bounds__(64) void k_readout(
    const float* __restrict__ X, const float* __restrict__ out_W,
    const float* __restrict__ out_b, const float* __restrict__ past,
    float* __restrict__ cur, float* __restrict__ ndb, float* __restrict__ out,
    int rows_per_b, int s, int init)
{
  const int b = blockIdx.x, lane = threadIdx.x;
  const int row = b * rows_per_b + rows_per_b - 1;
  float p0 = 0.f, p1 = 0.f;
  for (int d = lane; d < DMODEL; d += 64) {
    const float xv = X[(size_t)row * DMODEL + d];
    p0 += xv * out_W[d];
    p1 += xv * out_W[DMODEL + d];
  }
  p0 = wave_sum64(p0);
  p1 = wave_sum64(p1);
  if (lane == 0) {
    const float nd0 = p0 + out_b[0];
    const float nd1 = p1 + out_b[1];
    float c0, c1;
    if (init) {
      c0 = past[((size_t)b * PAST_N + PAST_N - 1) * 2 + 0];
      c1 = past[((size_t)b * PAST_N + PAST_N - 1) * 2 + 1];
    } else {
      c0 = cur[b * 2 + 0];
      c1 = cur[b * 2 + 1];
    }
    c0 += nd0; c1 += nd1;
    cur[b * 2 + 0] = c0; cur[b * 2 + 1] = c1;
    ndb[b * 2 + 0] = nd0; ndb[b * 2 + 1] = nd1;
    out[((size_t)b * FUT_N + s) * 2 + 0] = c0;
    out[((size_t)b * FUT_N + s) * 2 + 1] = c1;
  }
}

// ======================= decode weight pre-pack (uint4, 8 bf16 each) =======
// Wp4[k8 * N + n] = {pair(k=8k8+0,1), pair(2,3), pair(4,5), pair(6,7)} of column n
__global__ __launch_bounds__(256) void k_pack_decode4(
    const float* __restrict__ sa_Wqkv, const float* __restrict__ sa_Wo,
    const float* __restrict__ ca_Wqkv, const float* __restrict__ ca_Wo,
    const float* __restrict__ ff1_W, const float* __restrict__ ff2_W,
    uint4* __restrict__ Wp4)
{
  const int g = blockIdx.x * 256 + threadIdx.x;
  if (g >= TOTAL4) return;
  const float* src;
  if (g < CKV4_OFF) {
    const int l = g / LSTRIDE4, r = g % LSTRIDE4;
    if (r < OFF4_WO)       { int rr = r;             int k8 = rr / 768;  int n = rr % 768;  src = sa_Wqkv + (size_t)l * 196608 + (size_t)n * 256  + 8 * k8; }
    else if (r < OFF4_CAQ) { int rr = r - OFF4_WO;   int k8 = rr / 256;  int n = rr % 256;  src = sa_Wo   + (size_t)l * 65536  + (size_t)n * 256  + 8 * k8; }
    else if (r < OFF4_CAO) { int rr = r - OFF4_CAQ;  int k8 = rr / 256;  int n = rr % 256;  src = ca_Wqkv + (size_t)l * 196608 + (size_t)n * 256  + 8 * k8; }
    else if (r < OFF4_FF1) { int rr = r - OFF4_CAO;  int k8 = rr / 256;  int n = rr % 256;  src = ca_Wo   + (size_t)l * 65536  + (size_t)n * 256  + 8 * k8; }
    else if (r < OFF4_FF2) { int rr = r - OFF4_FF1;  int k8 = rr / 1024; int n = rr % 1024; src = ff1_W   + (size_t)l * 262144 + (size_t)n * 256  + 8 * k8; }
    else                   { int rr = r - OFF4_FF2;  int k8 = rr / 256;  int n = rr % 256;  src = ff2_W   + (size_t)l * 262144 + (size_t)n * 1024 + 8 * k8; }
  } else {
    const int r = g - CKV4_OFF;
    const int k8 = r / 1536, n = r % 1536;
    const int j = n >> 8, dcol = n & 255, l = j >> 1, kv = j & 1;
    src = ca_Wqkv + (size_t)l * 196608 + (size_t)(256 + kv * 256 + dcol) * 256 + 8 * k8;
  }
  uint4 u;
  u.x = ((uint32_t)f2bf(src[1]) << 16) | (uint32_t)f2bf(src[0]);
  u.y = ((uint32_t)f2bf(src[3]) << 16) | (uint32_t)f2bf(src[2]);
  u.z = ((uint32_t)f2bf(src[5]) << 16) | (uint32_t)f2bf(src[4]);
  u.w = ((uint32_t)f2bf(src[7]) << 16) | (uint32_t)f2bf(src[6]);
  Wp4[g] = u;
}

// ======================= fused 19-step decode =======================
// one workgroup (512 thr = 8 waves) per batch element; runs steps 1..19 internally
__global__ __launch_bounds__(NT) void k_decode(
    const uint4* __restrict__ Wp4, const float* __restrict__ bckv,
    const float* __restrict__ in_W, const float* __restrict__ in_b,
    const float* __restrict__ pos_emb,
    const float* __restrict__ ln0_w, const float* __restrict__ ln0_b,
    const float* __restrict__ sa_bqkv, const float* __restrict__ sa_bo,
    const float* __restrict__ ca_bqkv, const float* __restrict__ ca_bo,
    const float* __restrict__ ff1_b, const float* __restrict__ ff2_b,
    const float* __restrict__ ln1_w, const float* __restrict__ ln1_b,
    const float* __restrict__ ln2_w, const float* __restrict__ ln2_b,
    const float* __restrict__ ln3_w, const float* __restrict__ ln3_b,
    const float* __restrict__ out_W, const float* __restrict__ out_b,
    __hip_bfloat16* __restrict__ Ksa, __hip_bfloat16* __restrict__ Vsa,
    __hip_bfloat16* __restrict__ C6,
    const float* __restrict__ ndb, const float* __restrict__ cur,
    float* __restrict__ out)
{
  const int b = blockIdx.x;
  const int tid = threadIdx.x;
  const size_t slab = (size_t)BATCH * S_TOT * DMODEL;

  __shared__ __align__(16) float x[256];
  __shared__ __align__(16) float xt[256];
  __shared__ __align__(16) float q[256];
  __shared__ __align__(16) float att[256];
  __shared__ __align__(16) float hbuf[1024];
  __shared__ float pred[NT];
  __shared__ float kn[256], vn[256];
  __shared__ __align__(16) float ckvn[1536];
  __shared__ float ss[8][72];
  __shared__ float sb[8], sb2[8];
  __shared__ float ndc[4];

  if (tid == 0) {
    ndc[0] = ndb[2 * b];     ndc[1] = ndb[2 * b + 1];
    ndc[2] = cur[2 * b];     ndc[3] = cur[2 * b + 1];
  }
  __syncthreads();

  auto ln_row = [&](float* row, const float* g, const float* bb) {
    float v = (tid < 256) ? row[tid] : 0.f;
    float s  = wave_sum64(v);
    float s2 = wave_sum64(v * v);
    if ((tid & 63) == 0) { sb[tid >> 6] = s; sb2[tid >> 6] = s2; }
    __syncthreads();
    float mean = (sb[0] + sb[1] + sb[2] + sb[3]) * (1.0f / 256.0f);
    float ex2  = (sb2[0] + sb2[1] + sb2[2] + sb2[3]) * (1.0f / 256.0f);
    float var = ex2 - mean * mean;
    if (tid < 256) row[tid] = (v - mean) * rsqrtf(var + 1e-5f) * g[tid] + bb[tid];
    __syncthreads();
  };

  // GEMV K=256: uint4 weights [32][N], x from LDS as float4 (wave-uniform broadcast)
  auto gemvN = [&](const uint4* Wp, int N, const float* xin, auto&& emit) {
    const float4* x4 = (const float4*)xin;
    for (int n = tid; n < N; n += NT) {
      const uint4* col = Wp + n;
      float a0 = 0.f, a1 = 0.f, a2 = 0.f, a3 = 0.f;
#pragma unroll 8
      for (int k8 = 0; k8 < 32; k8++) {
        const uint4 w = col[(size_t)k8 * N];
        const float4 xa = x4[2 * k8];
        const float4 xb = x4[2 * k8 + 1];
        a0 += bl16(w.x) * xa.x + bh16(w.x) * xa.y;
        a1 += bl16(w.y) * xa.z + bh16(w.y) * xa.w;
        a2 += bl16(w.z) * xb.x + bh16(w.z) * xb.y;
        a3 += bl16(w.w) * xb.z + bh16(w.w) * xb.w;
      }
      emit(n, (a0 + a1) + (a2 + a3));
    }
  };

  // GEMV N=256, split-K across the two 256-thread halves -> pred[]
  auto gemv256 = [&](const uint4* Wp, int K8total, const float* xin) {
    const float4* x4 = (const float4*)xin;
    const int n = tid & 255, half = tid >> 8;
    const int kb = half * (K8total >> 1), ke = kb + (K8total >> 1);
    const uint4* col = Wp + n;
    float a0 = 0.f, a1 = 0.f, a2 = 0.f, a3 = 0.f;
#pragma unroll 8
    for (int k8 = kb; k8 < ke; k8++) {
      const uint4 w = col[(size_t)k8 * 256];
      const float4 xa = x4[2 * k8];
      const float4 xb = x4[2 * k8 + 1];
      a0 += bl16(w.x) * xa.x + bh16(w.x) * xa.y;
      a1 += bl16(w.y) * xa.z + bh16(w.y) * xa.w;
      a2 += bl16(w.z) * xb.x + bh16(w.z) * xb.y;
      a3 += bl16(w.w) * xb.z + bh16(w.w) * xb.w;
    }
    pred[tid] = (a0 + a1) + (a2 + a3);
  };

  // attention: 1 wave = 1 head; keys 0..pos-1 from bf16 cache, key pos from LDS
  auto attn8 = [&](const __hip_bfloat16* Kc, const __hip_bfloat16* Vc,
                   const float* knw, const float* vnw, int pos) {
    const int h = tid >> 6, lane = tid & 63;
    const float* qh = q + h * 32;
    float mx = -1e30f;
    for (int k0 = lane; k0 <= pos; k0 += 64) {
      float s = 0.f;
      if (k0 == pos) {
        const float* kp = knw + h * 32;
#pragma unroll
        for (int i = 0; i < 32; i++) s += qh[i] * kp[i];
      } else {
        const uint32_t* kp = (const uint32_t*)(Kc + ((size_t)b * S_TOT + k0) * DMODEL + h * 32);
#pragma unroll
        for (int i = 0; i < 16; i++) {
          uint32_t w = kp[i];
          s += bl16(w) * qh[2 * i];
          s += bh16(w) * qh[2 * i + 1];
        }
      }
      s *= 0.17677669529663687f;
      ss[h][k0] = s;
      mx = fmaxf(mx, s);
    }
    mx = wave_max64(mx);
    float sum = 0.f;
    for (int k0 = lane; k0 <= pos; k0 += 64) {
      float e = __expf(ss[h][k0] - mx);
      ss[h][k0] = e;
      sum += e;
    }
    sum = wave_sum64(sum);
    const float inv = 1.0f / sum;
    if (lane < 32) {
      float o = 0.f;
      for (int k0 = 0; k0 < pos; k0++)
        o += ss[h][k0] * __bfloat162float(Vc[((size_t)b * S_TOT + k0) * DMODEL + h * 32 + lane]);
      o += ss[h][pos] * vnw[h * 32 + lane];
      att[h * 32 + lane] = o * inv;
    }
  };

  for (int s = 1; s < FUT_N; s++) {
    const int pos = PAST_N - 1 + s;
    if (tid < 256) {
      xt[tid] = in_W[tid * 2] * ndc[0] + in_W[tid * 2 + 1] * ndc[1] + in_b[tid] +
                pos_emb[(size_t)pos * DMODEL + tid];
    }
    __syncthreads();
    ln_row(xt, ln0_w, ln0_b);
    if (tid < 256) x[tid] = xt[tid];
    __syncthreads();
    // CA K/V for this token: append to C6 + keep in LDS
    gemvN(Wp4 + CKV4_OFF, 1536, xt, [&](int n, float acc) {
      float v = acc + bckv[n];
      ckvn[n] = v;
      const int j = n >> 8;
      C6[(size_t)j * slab + ((size_t)b * S_TOT + pos) * DMODEL + (n & 255)] = __float2bfloat16(v);
    });
    __syncthreads();

    for (int l = 0; l < LAYERS; l++) {
      const uint4* Wl = Wp4 + (size_t)l * LSTRIDE4;
      // a. SA qkv
      gemvN(Wl + OFF4_QKV, 768, x, [&](int n, float acc) {
        float v = acc + sa_bqkv[l * 768 + n];
        if (n < 256) q[n] = v;
        else if (n < 512) {
          kn[n - 256] = v;
          Ksa[(size_t)l * slab + ((size_t)b * S_TOT + pos) * DMODEL + (n - 256)] = __float2bfloat16(v);
        } else {
          vn[n - 512] = v;
          Vsa[(size_t)l * slab + ((size_t)b * S_TOT + pos) * DMODEL + (n - 512)] = __float2bfloat16(v);
        }
      });
      __syncthreads();
      // b. SA attention
      attn8(Ksa + (size_t)l * slab, Vsa + (size_t)l * slab, kn, vn, pos);
      __syncthreads();
      // c. Wo + residual + LN1
      gemv256(Wl + OFF4_WO, 32, att);
      __syncthreads();
      if (tid < 256) x[tid] = x[tid] + pred[tid] + pred[tid + 256] + sa_bo[l * 256 + tid];
      __syncthreads();
      ln_row(x, ln1_w + l * 256, ln1_b + l * 256);
      // d. CA q
      gemv256(Wl + OFF4_CAQ, 32, x);
      __syncthreads();
      if (tid < 256) q[tid] = pred[tid] + pred[tid + 256] + ca_bqkv[l * 768 + tid];
      __syncthreads();
      // e. CA attention over C6 caches
      attn8(C6 + (size_t)(2 * l) * slab, C6 + (size_t)(2 * l + 1) * slab,
            ckvn + l * 512, ckvn + l * 512 + 256, pos);
      __syncthreads();
      // f. CA Wo + residual + LN2
      gemv256(Wl + OFF4_CAO, 32, att);
      __syncthreads();
      if (tid < 256) x[tid] = x[tid] + pred[tid] + pred[tid + 256] + ca_bo[l * 256 + tid];
      __syncthreads();
      ln_row(x, ln2_w + l * 256, ln2_b + l * 256);
      // g. FF1 + gelu
      gemvN(Wl + OFF4_FF1, 1024, x, [&](int n, float acc) {
        hbuf[n] = gelu_f(acc + ff1_b[l * 1024 + n]);
      });
      __syncthreads();
      // h. FF2 (K=1024) + residual + LN3
      gemv256(Wl + OFF4_FF2, 128, hbuf);
      __syncthreads();
      if (tid < 256) x[tid] = x[tid] + pred[tid] + pred[tid + 256] + ff2_b[l * 256 + tid];
      __syncthreads();
      ln_row(x, ln3_w + l * 256, ln3_b + l * 256);
    }

    // readout
    {
      const int lane = tid & 63;
      if (tid < 128) {
        const int d0 = tid >> 6;
        float p = 0.f;
        for (int d = lane; d < DMODEL; d += 64) p += x[d] * out_W[d0 * DMODEL + d];
        p = wave_sum64(p);
        if (lane == 0) {
          const float nd = p + out_b[d0];
          ndc[d0] = nd;
          const float c = ndc[2 + d0] + nd;
          ndc[2 + d0] = c;
          out[((size_t)b * FUT_N + s) * 2 + d0] = c;
        }
      }
      __syncthreads();
    }
  }
}

// ======================= host launch =======================
extern "C" void kernel_launch(void* const* d_in, const int* in_sizes, int n_in,
                              void* d_out, int out_size, void* d_ws, size_t ws_size,
                              hipStream_t stream)
{
  const float* past    = (const float*)d_in[0];
  const float* in_W    = (const float*)d_in[1];
  const float* in_b    = (const float*)d_in[2];
  const float* pos_emb = (const float*)d_in[3];
  const float* ln0_w   = (const float*)d_in[4];
  const float* ln0_b   = (const float*)d_in[5];
  const float* sa_Wqkv = (const float*)d_in[6];
  const float* sa_bqkv = (const float*)d_in[7];
  const float* sa_Wo   = (const float*)d_in[8];
  const float* sa_bo   = (const float*)d_in[9];
  const float* ca_Wqkv = (const float*)d_in[10];
  const float* ca_bqkv = (const float*)d_in[11];
  const float* ca_Wo   = (const float*)d_in[12];
  const float* ca_bo   = (const float*)d_in[13];
  const float* ff1_W   = (const float*)d_in[14];
  const float* ff1_b   = (const float*)d_in[15];
  const float* ff2_W   = (const float*)d_in[16];
  const float* ff2_b   = (const float*)d_in[17];
  const float* ln1_w   = (const float*)d_in[18];
  const float* ln1_b   = (const float*)d_in[19];
  const float* ln2_w   = (const float*)d_in[20];
  const float* ln2_b   = (const float*)d_in[21];
  const float* ln3_w   = (const float*)d_in[22];
  const float* ln3_b   = (const float*)d_in[23];
  const float* out_W   = (const float*)d_in[24];
  const float* out_b   = (const float*)d_in[25];
  float* out = (float*)d_out;

  const size_t Mpre = (size_t)BATCH * PAST_N;              // 6400
  const size_t slab = (size_t)BATCH * S_TOT * DMODEL;      // 2,293,760

  float* ws_f = (float*)d_ws;
  float* A    = ws_f;
  float* Bb   = A + Mpre * DMODEL;
  float* qb   = Bb + Mpre * DMODEL;
  float* at   = qb + Mpre * DMODEL;
  float* hb   = at + Mpre * DMODEL;
  float* Wckv = hb + Mpre * FFD;
  float* bckv = Wckv + (size_t)1536 * 256;
  float* ndb  = bckv + 1536;
  float* cur  = ndb + 256;
  __hip_bfloat16* Ksa = (__hip_bfloat16*)(cur + 256);
  __hip_bfloat16* Vsa = Ksa + 3 * slab;
  __hip_bfloat16* C6  = Vsa + 3 * slab;
  uint4* Wp4 = (uint4*)hb;  // aliases hb: free after prefill, used only by decode

  const size_t need = ((size_t)(C6 + 6 * slab) - (size_t)d_ws);
  if (ws_size < need) return;

  auto layer = [&](int l, int M, int rpb, int pbase) {
    const float* Wqkv = sa_Wqkv + (size_t)l * 768 * 256;
    __hip_bfloat16* kcl = Ksa + (size_t)l * slab;
    __hip_bfloat16* vcl = Vsa + (size_t)l * slab;
    k_gemm<<<dim3(768 / BN, M / BM), 256, 0, stream>>>(
        A, Wqkv, sa_bqkv + l * 768, nullptr, nullptr, M, 768, 256, 0, 1,
        qb, kcl, vcl, nullptr, rpb, pbase);
    k_attn<<<M * HEADS, 64, 0, stream>>>(qb, kcl, vcl, at, rpb, pbase);
    k_gemm<<<dim3(256 / BN, M / BM), 256, 0, stream>>>(
        at, sa_Wo + (size_t)l * 65536, sa_bo + l * 256, A, Bb, M, 256, 256, 0, 0,
        nullptr, nullptr, nullptr, nullptr, 1, 0);
    k_ln<<<M, 256, 0, stream>>>(Bb, ln1_w + l * 256, ln1_b + l * 256, A);
    k_gemm<<<dim3(256 / BN, M / BM), 256, 0, stream>>>(
        A, ca_Wqkv + (size_t)l * 768 * 256, ca_bqkv + l * 768, nullptr, qb,
        M, 256, 256, 0, 0, nullptr, nullptr, nullptr, nullptr, 1, 0);
    k_attn<<<M * HEADS, 64, 0, stream>>>(
        qb, C6 + (size_t)(2 * l) * slab, C6 + (size_t)(2 * l + 1) * slab, at, rpb, pbase);
    k_gemm<<<dim3(256 / BN, M / BM), 256, 0, stream>>>(
        at, ca_Wo + (size_t)l * 65536, ca_bo + l * 256, A, Bb, M, 256, 256, 0, 0,
        nullptr, nullptr, nullptr, nullptr, 1, 0);
    k_ln<<<M, 256, 0, stream>>>(Bb, ln2_w + l * 256, ln2_b + l * 256, A);
    k_gemm<<<dim3(FFD / BN, M / BM), 256, 0, stream>>>(
        A, ff1_W + (size_t)l * FFD * 256, ff1_b + l * FFD, nullptr, hb,
        M, FFD, 256, 1, 0, nullptr, nullptr, nullptr, nullptr, 1, 0);
    k_gemm<<<dim3(256 / BN, M / BM), 256, 0, stream>>>(
        hb, ff2_W + (size_t)l * 256 * FFD, ff2_b + l * 256, A, Bb, M, 256, FFD, 0, 0,
        nullptr, nullptr, nullptr, nullptr, 1, 0);
    k_ln<<<M, 256, 0, stream>>>(Bb, ln3_w + l * 256, ln3_b + l * 256, A);
  };

  // ---- prefill over past 50 positions ----
  k_prepack<<<1536, 256, 0, stream>>>(ca_Wqkv, ca_bqkv, Wckv, bckv);
  k_embed<<<(int)Mpre, 256, 0, stream>>>(past, in_W, in_b, pos_emb, ln0_w, ln0_b, A);
  k_gemm<<<dim3(1536 / BN, (int)Mpre / BM), 256, 0, stream>>>(
      A, Wckv, bckv, nullptr, nullptr, (int)Mpre, 1536, 256, 0, 2,
      nullptr, nullptr, nullptr, C6, PAST_N, 0);
  for (int l = 0; l < LAYERS; l++) layer(l, (int)Mpre, PAST_N, 0);
  k_readout<<<BATCH, 64, 0, stream>>>(A, out_W, out_b, past, cur, ndb, out, PAST_N, 0, 1);

  // ---- pack decode weights (into hb scratch, free after prefill) ----
  k_pack_decode4<<<TOTAL4 / 256, 256, 0, stream>>>(
      sa_Wqkv, sa_Wo, ca_Wqkv, ca_Wo, ff1_W, ff2_W, Wp4);

  // ---- fused 19-step decode: one WG per batch element ----
  k_decode<<<BATCH, NT, 0, stream>>>(
      Wp4, bckv, in_W, in_b, pos_emb, ln0_w, ln0_b,
      sa_bqkv, sa_bo, ca_bqkv, ca_bo, ff1_b, ff2_b,
      ln1_w, ln1_b, ln2_w, ln2_b, ln3_w, ln3_b,
      out_W, out_b, Ksa, Vsa, C6, ndb, cur, out);
}